// Round 11
// baseline (58.543 us; speedup 1.0000x reference)
//
#include <hip/hip_runtime.h>

// x[64][16][8192] f32, J=4, LEVELS=13, eps 1e-5.
// targets[j] = blockmean(2^(13-j)); inputs[j] = BN(blockmean(2^(13-j)) - blockmean(2^(14-j))), input[0]=BN(m0)
// Output [2][4][64][16][8192] f32.
// R5 structure (best: 53.1us) + SINGLE-VARIABLE change: nontemporal OUTPUT stores
// (register-sourced, no dependent loads) to test L2-bypass for the 268MB stream.

#define SSTR 16
// stats row: [0]=m0, [1..2]=m1, [3..6]=m2, [7..14]=m3  (level j at base (1<<j)-1, count 1<<j)

typedef float f32x4 __attribute__((ext_vector_type(4)));

__global__ __launch_bounds__(256) void stats_targets_kernel(const float* __restrict__ x,
                                                            float* __restrict__ stats,
                                                            f32x4* __restrict__ out) {
    int row = blockIdx.x;                 // 0..1023  (b=row>>4, c=row&15)
    int t = threadIdx.x;                  // 0..255
    int lane = t & 63, wave = t >> 6;
    const f32x4* xr = reinterpret_cast<const f32x4*>(x) + (size_t)row * 2048;
    float s[8];
#pragma unroll
    for (int k = 0; k < 8; ++k) {
        f32x4 v = __builtin_nontemporal_load(&xr[t + 256 * k]);  // iter k = 1024-block k
        s[k] = (v.x + v.y) + (v.z + v.w);
    }
    __shared__ float red[8][4];
    __shared__ float sb[16];
#pragma unroll
    for (int k = 0; k < 8; ++k) {
        float v = s[k];
#pragma unroll
        for (int off = 32; off; off >>= 1) v += __shfl_down(v, off, 64);
        if (lane == 0) red[k][wave] = v;
    }
    __syncthreads();
    if (t < 8) sb[7 + t] = (red[t][0] + red[t][1] + red[t][2] + red[t][3]) * (1.0f / 1024.0f);
    __syncthreads();
    if (t == 0) {
        float m2[4], m1[2];
#pragma unroll
        for (int k = 0; k < 4; ++k) m2[k] = 0.5f * (sb[7 + 2 * k] + sb[8 + 2 * k]);
        m1[0] = 0.5f * (m2[0] + m2[1]);
        m1[1] = 0.5f * (m2[2] + m2[3]);
        sb[0] = 0.5f * (m1[0] + m1[1]);
        sb[1] = m1[0]; sb[2] = m1[1];
        sb[3] = m2[0]; sb[4] = m2[1]; sb[5] = m2[2]; sb[6] = m2[3];
    }
    __syncthreads();
    if (t < 15) stats[(size_t)row * SSTR + t] = sb[t];
    float rv[15];
#pragma unroll
    for (int k = 0; k < 15; ++k) rv[k] = sb[k];
#pragma unroll
    for (int j = 0; j < 4; ++j) {         // targets (part=1)
        f32x4* orow = out + ((size_t)(4 + j) * 1024 + row) * 2048;
        int sh = 3 - j;
#pragma unroll
        for (int i = 0; i < 8; ++i) {
            float v = rv[(1 << j) - 1 + (i >> sh)];
            f32x4 q = {v, v, v, v};
            __builtin_nontemporal_store(q, &orow[t + (i << 8)]);
        }
    }
}

// block k (0..1023): j = k>>8, c = (k>>4)&15, b in {4*(k&15) .. +3}
__global__ __launch_bounds__(256) void inputs_kernel(const float* __restrict__ stats,
                                                     const float* __restrict__ gamma,
                                                     const float* __restrict__ beta,
                                                     f32x4* __restrict__ out) {
    int blk = blockIdx.x;
    int j = blk >> 8;
    int c = (blk >> 4) & 15;
    int bg = blk & 15;
    int t = threadIdx.x;
    __shared__ float ss[2];               // scale, shift
    if (t < 64) {                         // wave 0: bn reduce over 64 batch rows
        const float* s = stats + (size_t)((t << 4) + c) * SSTR;
        float sum = 0.f, sum2 = 0.f;
        float B = (float)(8192 >> j);
        if (j == 0) {
            float d = s[0];
            sum = d; sum2 = d * d;
        } else {
            int base = (1 << j) - 1, pb = (1 << (j - 1)) - 1;
            for (int k = 0; k < (1 << j); ++k) {
                float d = s[base + k] - s[pb + (k >> 1)];
                sum += d; sum2 += d * d;
            }
        }
        sum *= B; sum2 *= B;
#pragma unroll
        for (int off = 32; off; off >>= 1) {
            sum  += __shfl_down(sum, off, 64);
            sum2 += __shfl_down(sum2, off, 64);
        }
        if (t == 0) {
            const float N = 64.0f * 8192.0f;
            float mean = sum / N;
            float var = sum2 / N - mean * mean;
            float inv = rsqrtf(var + 1e-5f);
            float sc = gamma[(j << 4) + c] * inv;
            ss[0] = sc;
            ss[1] = beta[(j << 4) + c] - mean * sc;
        }
    }
    __syncthreads();
    float sc = ss[0], sh0 = ss[1];
    int shr = 3 - j;
#pragma unroll
    for (int bb = 0; bb < 4; ++bb) {
        int row = (((bg << 2) + bb) << 4) + c;
        const float* s = stats + (size_t)row * SSTR;
        float rv[8];
#pragma unroll
        for (int r = 0; r < 8; ++r) {
            int run = (r < (1 << j)) ? r : 0;
            float mj = s[(1 << j) - 1 + run];
            float d = (j == 0) ? mj : mj - s[(1 << (j - 1)) - 1 + (run >> 1)];
            rv[r] = d * sc + sh0;
        }
        f32x4* orow = out + ((size_t)j * 1024 + row) * 2048;
#pragma unroll
        for (int i = 0; i < 8; ++i) {
            float v = rv[i >> shr];
            f32x4 q = {v, v, v, v};
            __builtin_nontemporal_store(q, &orow[t + (i << 8)]);
        }
    }
}

extern "C" void kernel_launch(void* const* d_in, const int* in_sizes, int n_in,
                              void* d_out, int out_size, void* d_ws, size_t ws_size,
                              hipStream_t stream) {
    const float* x     = (const float*)d_in[0];
    const float* gamma = (const float*)d_in[1];
    const float* beta  = (const float*)d_in[2];
    f32x4* out = (f32x4*)d_out;
    float* stats = (float*)d_ws;          // 1024*16 floats = 64 KiB

    stats_targets_kernel<<<1024, 256, 0, stream>>>(x, stats, out);
    inputs_kernel<<<1024, 256, 0, stream>>>(stats, gamma, beta, out);
}

// Round 12
// 53.078 us; speedup vs baseline: 1.1029x; 1.1029x over previous
//
#include <hip/hip_runtime.h>

// x[64][16][8192] f32, J=4, LEVELS=13, eps 1e-5.
// targets[j] = blockmean(2^(13-j)); inputs[j] = BN(blockmean(2^(13-j)) - blockmean(2^(14-j))), input[0]=BN(m0)
// Output [2][4][64][16][8192] f32.
// == R5 configuration: best measured (53.1 us). Plain (L2-routed) output stores,
// register-hoisted run values, K1 = stats + target rows, K2 = inline-BN + input rows.

#define STATS_STRIDE 16
// stats row: [0]=m0, [1..2]=m1, [3..6]=m2, [7..14]=m3  (level j at base (1<<j)-1, count 1<<j)

typedef float f32x4 __attribute__((ext_vector_type(4)));

__global__ __launch_bounds__(256) void stats_targets_kernel(const float* __restrict__ x,
                                                            float* __restrict__ stats,
                                                            f32x4* __restrict__ out) {
    int row = blockIdx.x;                 // 0..1023  (b=row>>4, c=row&15)
    int t = threadIdx.x;                  // 0..255
    int lane = t & 63, wave = t >> 6;
    const f32x4* xr = reinterpret_cast<const f32x4*>(x) + (size_t)row * 2048;
    float s[8];
#pragma unroll
    for (int k = 0; k < 8; ++k) {
        f32x4 v = __builtin_nontemporal_load(&xr[t + 256 * k]);  // iter k = 1024-block k
        s[k] = (v.x + v.y) + (v.z + v.w);
    }
    __shared__ float red[8][4];
    __shared__ float sb[16];
#pragma unroll
    for (int k = 0; k < 8; ++k) {
        float v = s[k];
#pragma unroll
        for (int off = 32; off; off >>= 1) v += __shfl_down(v, off, 64);
        if (lane == 0) red[k][wave] = v;
    }
    __syncthreads();
    if (t < 8) sb[7 + t] = (red[t][0] + red[t][1] + red[t][2] + red[t][3]) * (1.0f / 1024.0f);
    __syncthreads();
    if (t == 0) {
        float m2[4], m1[2];
#pragma unroll
        for (int k = 0; k < 4; ++k) m2[k] = 0.5f * (sb[7 + 2 * k] + sb[8 + 2 * k]);
        m1[0] = 0.5f * (m2[0] + m2[1]);
        m1[1] = 0.5f * (m2[2] + m2[3]);
        sb[0] = 0.5f * (m1[0] + m1[1]);
        sb[1] = m1[0]; sb[2] = m1[1];
        sb[3] = m2[0]; sb[4] = m2[1]; sb[5] = m2[2]; sb[6] = m2[3];
    }
    __syncthreads();
    if (t < 15) stats[(size_t)row * STATS_STRIDE + t] = sb[t];
    float rv[15];
#pragma unroll
    for (int k = 0; k < 15; ++k) rv[k] = sb[k];
#pragma unroll
    for (int j = 0; j < 4; ++j) {         // targets (part=1)
        f32x4* orow = out + ((size_t)(4 + j) * 1024 + row) * 2048;
        int sh = 3 - j;
#pragma unroll
        for (int i = 0; i < 8; ++i) {
            float v = rv[(1 << j) - 1 + (i >> sh)];
            f32x4 q = {v, v, v, v};
            orow[t + (i << 8)] = q;
        }
    }
}

// block k (0..1023): j = k>>8, c = (k>>4)&15, b in {4*(k&15) .. +3}
__global__ __launch_bounds__(256) void inputs_kernel(const float* __restrict__ stats,
                                                     const float* __restrict__ gamma,
                                                     const float* __restrict__ beta,
                                                     f32x4* __restrict__ out) {
    int blk = blockIdx.x;
    int j = blk >> 8;
    int c = (blk >> 4) & 15;
    int bg = blk & 15;
    int t = threadIdx.x;
    __shared__ float ss[2];               // scale, shift
    if (t < 64) {                         // wave 0: bn reduce over 64 batch rows
        const float* s = stats + (size_t)((t << 4) + c) * STATS_STRIDE;
        float sum = 0.f, sum2 = 0.f;
        float B = (float)(8192 >> j);
        if (j == 0) {
            float d = s[0];
            sum = d; sum2 = d * d;
        } else {
            int base = (1 << j) - 1, pb = (1 << (j - 1)) - 1;
            for (int k = 0; k < (1 << j); ++k) {
                float d = s[base + k] - s[pb + (k >> 1)];
                sum += d; sum2 += d * d;
            }
        }
        sum *= B; sum2 *= B;
#pragma unroll
        for (int off = 32; off; off >>= 1) {
            sum  += __shfl_down(sum, off, 64);
            sum2 += __shfl_down(sum2, off, 64);
        }
        if (t == 0) {
            const float N = 64.0f * 8192.0f;
            float mean = sum / N;
            float var = sum2 / N - mean * mean;
            float inv = rsqrtf(var + 1e-5f);
            float sc = gamma[(j << 4) + c] * inv;
            ss[0] = sc;
            ss[1] = beta[(j << 4) + c] - mean * sc;
        }
    }
    __syncthreads();
    float sc = ss[0], sh0 = ss[1];
    int shr = 3 - j;
#pragma unroll
    for (int bb = 0; bb < 4; ++bb) {
        int row = (((bg << 2) + bb) << 4) + c;
        const float* s = stats + (size_t)row * STATS_STRIDE;
        float rv[8];
#pragma unroll
        for (int r = 0; r < 8; ++r) {
            int run = (r < (1 << j)) ? r : 0;
            float mj = s[(1 << j) - 1 + run];
            float d = (j == 0) ? mj : mj - s[(1 << (j - 1)) - 1 + (run >> 1)];
            rv[r] = d * sc + sh0;
        }
        f32x4* orow = out + ((size_t)j * 1024 + row) * 2048;
#pragma unroll
        for (int i = 0; i < 8; ++i) {
            float v = rv[i >> shr];
            f32x4 q = {v, v, v, v};
            orow[t + (i << 8)] = q;
        }
    }
}

extern "C" void kernel_launch(void* const* d_in, const int* in_sizes, int n_in,
                              void* d_out, int out_size, void* d_ws, size_t ws_size,
                              hipStream_t stream) {
    const float* x     = (const float*)d_in[0];
    const float* gamma = (const float*)d_in[1];
    const float* beta  = (const float*)d_in[2];
    f32x4* out = (f32x4*)d_out;
    float* stats = (float*)d_ws;          // 1024*16 floats = 64 KiB

    stats_targets_kernel<<<1024, 256, 0, stream>>>(x, stats, out);
    inputs_kernel<<<1024, 256, 0, stream>>>(stats, gamma, beta, out);
}